// Round 3
// baseline (704.183 us; speedup 1.0000x reference)
//
#include <hip/hip_runtime.h>
#include <math.h>

#define B_   128
#define L_   336
#define N_   321
#define E_   128
#define LAT_ 64

typedef float f4 __attribute__((ext_vector_type(4)));

// out layout (flat concat, fp32):
#define OUT_HH  (B_*N_*E_)
#define OUT_MU  (2*B_*N_*E_)
#define OUT_VAR (2*B_*N_*E_ + B_*N_*LAT_)

// ---------------------------------------------------------------------------
// Kernel 1: transpose x[B][L][N] -> xp2[N][L][B]  (b innermost so the GEMM's
// A-tile staging is contiguous). Tile: 32n x 32b x 4l per 256-thread block.
// (x rows are 321 floats -> only 4B-aligned, so loads along n must be scalar.)
// ---------------------------------------------------------------------------
__global__ __launch_bounds__(256) void k_transpose(const float* __restrict__ x,
                                                   float* __restrict__ xp2) {
    __shared__ float t[4][32][33];   // [l][n][b], stride 33 -> <=2-way conflicts
    const int n0 = blockIdx.x * 32;
    const int b0 = blockIdx.y * 32;
    const int l0 = blockIdx.z * 4;
    const int tid = threadIdx.x;
    const int tn = tid & 31;
    const int tb = tid >> 5;         // 0..7
    const int nn = n0 + tn;

    if (nn < N_) {
#pragma unroll
        for (int l = 0; l < 4; ++l)
#pragma unroll
            for (int p = 0; p < 4; ++p) {
                const int b = b0 + tb + 8 * p;
                t[l][tn][tb + 8 * p] = x[(size_t)b * (L_ * N_) + (size_t)(l0 + l) * N_ + nn];
            }
    }
    __syncthreads();
#pragma unroll
    for (int p = 0; p < 4; ++p) {
        const int idx = tid + 256 * p;
        const int row = idx >> 3;        // 0..127 = l*32 + n2
        const int bq  = idx & 7;
        const int l   = row >> 5;
        const int n2  = row & 31;
        if (n0 + n2 < N_) {
            f4 v;
#pragma unroll
            for (int j = 0; j < 4; ++j) v[j] = t[l][n2][bq * 4 + j];
            *(f4*)(xp2 + (size_t)(n0 + n2) * (L_ * B_) + (size_t)(l0 + l) * B_ + b0 + bq * 4) = v;
        }
    }
}

// ---------------------------------------------------------------------------
// Kernel 2: fused grouped GEMM. 256 threads (4 waves); tile 32 rows x 128 cols.
// grid = N*4 = 1284 (~5 blocks/CU with 32KB LDS + launch_bounds(256,5)).
// Per thread: acc[4][4]. Register-prefetch pipeline: next chunk's global loads
// issue right after the LDS-ready barrier and drain under 512 FMAs.
// LDS: A2t[128][32] (h_hat^T, slot-swizzled; stage-1 A1[32][32] aliases front)
//      + Wbuf[32][128].
// ---------------------------------------------------------------------------
#define KT  32
#define NCH ((L_ + KT - 1) / KT)   // 11 (last chunk zero-padded)

template <bool XP>
__global__ __launch_bounds__(256, 5) void k_fused(const float* __restrict__ xsrc,
                                                  const float* __restrict__ time_x,
                                                  const float* __restrict__ W_embed,
                                                  const float* __restrict__ b_embed,
                                                  const float* __restrict__ W_mu,
                                                  const float* __restrict__ b_mu,
                                                  const float* __restrict__ W_var,
                                                  const float* __restrict__ b_var,
                                                  float* __restrict__ out) {
    __shared__ float A2t[128 * 32];    // 16KB; stage-1 A1[32][32] aliases front 4KB
    __shared__ float Wbuf[KT * 128];   // 16KB
    float* A1 = A2t;

    const int tid  = threadIdx.x;
    const int tx   = tid & 31;         // col group (4 cols)
    const int trow = tid >> 5;         // 0..7, row group (4 rows)

    // bijective XCD swizzle (nwg = 1284 = 8*160 + 4)
    int bid = blockIdx.x;
    {
        const int nwg = N_ * 4, q = nwg / 8, r = nwg % 8;
        const int xcd = bid & 7, lid = bid >> 3;
        bid = (xcd < r ? xcd * (q + 1) : r * (q + 1) + (xcd - r) * q) + lid;
    }
    const int n  = bid >> 2;
    const int b0 = (bid & 3) * 32;

    const int al = tid >> 3;           // l within chunk (0..31)
    const int ab = tid & 7;            // b f4-chunk
    const int wr = tid >> 5;           // W row (+8p)
    const int wc = tid & 31;           // W col f4-chunk

    const float* Wemb  = W_embed + (size_t)n * (L_ * E_);
    const float* Wmu_n = W_mu  + (size_t)n * (E_ * LAT_);
    const float* Wvar_n= W_var + (size_t)n * (E_ * LAT_);

    float acc[4][4];
#pragma unroll
    for (int i = 0; i < 4; ++i)
#pragma unroll
        for (int j = 0; j < 4; ++j) acc[i][j] = 0.f;

    f4 rA, rW[4];
    // ---- prefetch chunk 0 ----
    {
        const int k = al;
        if (XP) {
            rA = *(const f4*)(xsrc + (size_t)n * (L_ * B_) + (size_t)k * B_ + b0 + ab * 4);
        } else {
#pragma unroll
            for (int j = 0; j < 4; ++j)
                rA[j] = xsrc[(size_t)(b0 + ab * 4 + j) * (L_ * N_) + (size_t)k * N_ + n];
        }
#pragma unroll
        for (int p = 0; p < 4; ++p)
            rW[p] = *(const f4*)(Wemb + (size_t)(wr + 8 * p) * E_ + wc * 4);
    }

    // ------------------------- stage 1: h, K = 336 -------------------------
    for (int it = 0; it < NCH; ++it) {
        __syncthreads();                       // prev chunk's readers done
        *(f4*)(A1 + al * 32 + ab * 4) = rA;
#pragma unroll
        for (int p = 0; p < 4; ++p)
            *(f4*)(Wbuf + (wr + 8 * p) * 128 + wc * 4) = rW[p];
        __syncthreads();                       // chunk visible

        if (it + 1 < NCH) {                    // issue next chunk's loads now
            const int k0 = (it + 1) * KT;
            const int k  = k0 + al;
            f4 z = {0.f, 0.f, 0.f, 0.f};
            if (k < L_) {
                if (XP) {
                    z = *(const f4*)(xsrc + (size_t)n * (L_ * B_) + (size_t)k * B_ + b0 + ab * 4);
                } else {
#pragma unroll
                    for (int j = 0; j < 4; ++j)
                        z[j] = xsrc[(size_t)(b0 + ab * 4 + j) * (L_ * N_) + (size_t)k * N_ + n];
                }
            }
            rA = z;
#pragma unroll
            for (int p = 0; p < 4; ++p) {
                const int kw = k0 + wr + 8 * p;
                f4 zw = {0.f, 0.f, 0.f, 0.f};
                if (kw < L_) zw = *(const f4*)(Wemb + (size_t)kw * E_ + wc * 4);
                rW[p] = zw;
            }
        }

#pragma unroll
        for (int kk = 0; kk < KT; ++kk) {
            f4 a = *(const f4*)(A1 + kk * 32 + trow * 4);      // broadcast
            f4 w = *(const f4*)(Wbuf + kk * 128 + tx * 4);
#pragma unroll
            for (int i = 0; i < 4; ++i)
#pragma unroll
                for (int j = 0; j < 4; ++j) acc[i][j] += a[i] * w[j];
        }
    }
    __syncthreads();   // stage-1 LDS readers done before A2t overwrite

    // ---- prefetch stage-2 W chunk 0 (hides under epilogue-1) ----
    {
#pragma unroll
        for (int p = 0; p < 4; ++p) {
            const int e = wr + 8 * p;
            rW[p] = (wc < 16) ? *(const f4*)(Wmu_n  + (size_t)e * LAT_ + wc * 4)
                              : *(const f4*)(Wvar_n + (size_t)e * LAT_ + wc * 4 - 64);
        }
    }

    // --------- epilogue 1: bias, h, sigmoid(time_x)*h, h_hat^T -> LDS ------
    f4 bev = *(const f4*)(b_embed + n * E_ + tx * 4);
    f4 hh[4];
#pragma unroll
    for (int i = 0; i < 4; ++i) {
        const int row = b0 + trow * 4 + i;
        const size_t base = ((size_t)row * N_ + n) * E_ + tx * 4;
        f4 h;
#pragma unroll
        for (int j = 0; j < 4; ++j) h[j] = acc[i][j] + bev[j];
        __builtin_nontemporal_store(h, (f4*)(out + base));
        f4 tv = *(const f4*)(time_x + base);
        f4 hv;
#pragma unroll
        for (int j = 0; j < 4; ++j) hv[j] = h[j] * (1.f / (1.f + __expf(-tv[j])));
        __builtin_nontemporal_store(hv, (f4*)(out + OUT_HH + base));
        hh[i] = hv;
    }
    // h_hat^T -> A2t, element (e,r) at e*32 + slot*4 + (r&3), slot=(r>>2)^((e>>2)&7)
    {
        const int slotw = trow ^ (tx & 7);
#pragma unroll
        for (int j = 0; j < 4; ++j) {
            const int e = tx * 4 + j;
            f4 v;
#pragma unroll
            for (int q = 0; q < 4; ++q) v[q] = hh[q][j];
            *(f4*)(A2t + e * 32 + slotw * 4) = v;
        }
    }

    // ------------------- stage 2: [mu|var], K = E = 128 ---------------------
#pragma unroll
    for (int i = 0; i < 4; ++i)
#pragma unroll
        for (int j = 0; j < 4; ++j) acc[i][j] = 0.f;

    for (int c = 0; c < 4; ++c) {
        __syncthreads();   // c=0: A2t writes visible + stage-1 Wbuf readers done
#pragma unroll
        for (int p = 0; p < 4; ++p)
            *(f4*)(Wbuf + (wr + 8 * p) * 128 + wc * 4) = rW[p];
        __syncthreads();

        if (c + 1 < 4) {
            const int e0 = (c + 1) * KT;
#pragma unroll
            for (int p = 0; p < 4; ++p) {
                const int e = e0 + wr + 8 * p;
                rW[p] = (wc < 16) ? *(const f4*)(Wmu_n  + (size_t)e * LAT_ + wc * 4)
                                  : *(const f4*)(Wvar_n + (size_t)e * LAT_ + wc * 4 - 64);
            }
        }

#pragma unroll
        for (int kk = 0; kk < KT; ++kk) {
            const int slot = trow ^ (kk >> 2);                  // (e>>2)&7 with e=c*32+kk
            f4 a = *(const f4*)(A2t + (c * KT + kk) * 32 + slot * 4);  // broadcast
            f4 w = *(const f4*)(Wbuf + kk * 128 + tx * 4);
#pragma unroll
            for (int i = 0; i < 4; ++i)
#pragma unroll
                for (int j = 0; j < 4; ++j) acc[i][j] += a[i] * w[j];
        }
    }

    // ------------------------- epilogue 2: mu / var -------------------------
    f4 bb = (tx < 16) ? *(const f4*)(b_mu  + n * LAT_ + tx * 4)
                      : *(const f4*)(b_var + n * LAT_ + tx * 4 - 64);
#pragma unroll
    for (int i = 0; i < 4; ++i) {
        const int row = b0 + trow * 4 + i;
        const size_t base = ((size_t)row * N_ + n) * LAT_;
        f4 o;
#pragma unroll
        for (int j = 0; j < 4; ++j) o[j] = acc[i][j] + bb[j];
        if (tx < 16) __builtin_nontemporal_store(o, (f4*)(out + OUT_MU  + base + tx * 4));
        else         __builtin_nontemporal_store(o, (f4*)(out + OUT_VAR + base + tx * 4 - 64));
    }
}

// ---------------------------------------------------------------------------
extern "C" void kernel_launch(void* const* d_in, const int* in_sizes, int n_in,
                              void* d_out, int out_size, void* d_ws, size_t ws_size,
                              hipStream_t stream) {
    const float* x       = (const float*)d_in[0];
    const float* time_x  = (const float*)d_in[1];
    const float* W_embed = (const float*)d_in[2];
    const float* b_embed = (const float*)d_in[3];
    const float* W_mu    = (const float*)d_in[4];
    const float* b_mu    = (const float*)d_in[5];
    const float* W_var   = (const float*)d_in[6];
    const float* b_var   = (const float*)d_in[7];
    float* out = (float*)d_out;

    const size_t need = (size_t)N_ * L_ * B_ * sizeof(float);
    const int nblk = N_ * 4;   // 1284

    if (ws_size >= need) {
        float* xp2 = (float*)d_ws;
        k_transpose<<<dim3(11, 4, 84), 256, 0, stream>>>(x, xp2);
        k_fused<true><<<nblk, 256, 0, stream>>>(xp2, time_x, W_embed, b_embed,
                                                W_mu, b_mu, W_var, b_var, out);
    } else {
        k_fused<false><<<nblk, 256, 0, stream>>>(x, time_x, W_embed, b_embed,
                                                 W_mu, b_mu, W_var, b_var, out);
    }
}